// Round 3
// baseline (450.910 us; speedup 1.0000x reference)
//
#include <hip/hip_runtime.h>
#include <hip/hip_bf16.h>

typedef __attribute__((ext_vector_type(8))) short short8;
typedef __attribute__((ext_vector_type(4))) float f32x4;
typedef __attribute__((ext_vector_type(4))) unsigned short u16x4;
typedef __attribute__((ext_vector_type(4))) int int4v;
typedef __attribute__((ext_vector_type(2))) unsigned int u32x2;

#define DEVI static __device__ __forceinline__

constexpr int B_ = 4, S_ = 2048, D_ = 768, NH_ = 12, DH_ = 64;
constexpr int M_ = B_ * S_;                 // 8192
constexpr size_t NX = (size_t)M_ * D_;      // 6291456 elems
constexpr size_t NW = (size_t)D_ * D_;      // 589824 elems

DEVI unsigned short f2bf(float f) {
  union { float f; unsigned u; } c; c.f = f;
  unsigned u = c.u;
  return (unsigned short)((u + 0x7FFFu + ((u >> 16) & 1u)) >> 16);  // RNE
}

DEVI unsigned cvtpk_bf16(float lo, float hi) {
  unsigned r;
  asm("v_cvt_pk_bf16_f32 %0, %1, %2" : "=v"(r) : "v"(lo), "v"(hi));
  return r;  // low16 = bf16(lo), high16 = bf16(hi)
}

DEVI void gload16(const void* g, void* l) {
  __builtin_amdgcn_global_load_lds(
      (const __attribute__((address_space(1))) void*)g,
      (__attribute__((address_space(3))) void*)l, 16, 0, 0);
}

// ---------------------------------------------------------------- convert
// 1D packed grid: [0,18432) X segs, [18432,20736) W combined, [20736,20744) mask
__global__ __launch_bounds__(256) void convert_kernel(
    const float* __restrict__ q, const float* __restrict__ k,
    const float* __restrict__ v, const float* __restrict__ qw_,
    const float* __restrict__ kw_, const float* __restrict__ vw_,
    const float* __restrict__ ow_, const int* __restrict__ smask,
    unsigned short* __restrict__ Xq, unsigned short* __restrict__ Xk,
    unsigned short* __restrict__ Xv, unsigned short* __restrict__ Wc,
    float* __restrict__ dmask) {
  const long bid = blockIdx.x;
  const int tid = threadIdx.x;
  if (bid < 18432) {
    const int seg = (int)(bid / 6144);
    const long i = (bid % 6144) * 256 + tid;
    const float* src = seg == 0 ? q : seg == 1 ? k : v;
    unsigned short* dst = seg == 0 ? Xq : seg == 1 ? Xk : Xv;
    f32x4 vv = *(const f32x4*)(src + i * 4);
    u16x4 o;
    o.x = f2bf(vv.x); o.y = f2bf(vv.y); o.z = f2bf(vv.z); o.w = f2bf(vv.w);
    *(u16x4*)(dst + i * 4) = o;
  } else if (bid < 20736) {
    const long e = ((bid - 18432) * 256 + tid) * 4;  // elem in [0, 4*NW)
    const int j = (int)(e / (long)NW);
    const float* src = j == 0 ? qw_ : j == 1 ? kw_ : j == 2 ? vw_ : ow_;
    f32x4 vv = *(const f32x4*)(src + (e - (long)j * NW));
    u16x4 o;
    o.x = f2bf(vv.x); o.y = f2bf(vv.y); o.z = f2bf(vv.z); o.w = f2bf(vv.w);
    *(u16x4*)(Wc + e) = o;
  } else {
    const long i = (bid - 20736) * 256 + tid;
    int4v m = *(const int4v*)(smask + i * 4);
    f32x4 o;
    o.x = m.x ? 0.f : -1e30f; o.y = m.y ? 0.f : -1e30f;
    o.z = m.z ? 0.f : -1e30f; o.w = m.w ? 0.f : -1e30f;
    *(f32x4*)(dmask + i * 4) = o;
  }
}

// ---------------------------------------------------------------- gemm core
// C[128x128] tile of A[M,768] @ Bt[768,768]^T, bf16 MFMA 16x16x32.
// 4 waves, each 64x64 (4x4 fragments). BK=32, global_load_lds staging.
DEVI void gemm_core(const unsigned short* __restrict__ A,
                    const unsigned short* __restrict__ Bt,
                    unsigned short* As, unsigned short* Bs,
                    int m0, int n0, int tid, f32x4 acc[4][4]) {
  const int w = tid >> 6, l = tid & 63;
  const int wm = w >> 1, wn = w & 1;
  const int lr = l & 15, lg = l >> 4;

  const unsigned short* gA0 = A  + (size_t)(m0 + (tid >> 2)) * 768 + (tid & 3) * 8;
  const unsigned short* gB0 = Bt + (size_t)(n0 + (tid >> 2)) * 768 + (tid & 3) * 8;
  unsigned short* lA0 = As + (size_t)(w * 64) * 8;  // wave-uniform LDS base
  unsigned short* lB0 = Bs + (size_t)(w * 64) * 8;
  const unsigned short* fA = As + (size_t)(wm * 64 + lr) * 32 + lg * 8;
  const unsigned short* fB = Bs + (size_t)(wn * 64 + lr) * 32 + lg * 8;

  for (int k0 = 0; k0 < 768; k0 += 32) {
    __syncthreads();
    gload16(gA0 + k0, lA0);
    gload16(gA0 + (size_t)64 * 768 + k0, lA0 + 2048);
    gload16(gB0 + k0, lB0);
    gload16(gB0 + (size_t)64 * 768 + k0, lB0 + 2048);
    __syncthreads();
    short8 af[4], bf[4];
#pragma unroll
    for (int m = 0; m < 4; m++) af[m] = *(const short8*)(fA + m * 16 * 32);
#pragma unroll
    for (int n = 0; n < 4; n++) bf[n] = *(const short8*)(fB + n * 16 * 32);
#pragma unroll
    for (int m = 0; m < 4; m++)
#pragma unroll
      for (int n = 0; n < 4; n++)
        acc[m][n] = __builtin_amdgcn_mfma_f32_16x16x32_bf16(af[m], bf[n], acc[m][n], 0, 0, 0);
  }
}

// ---------------------------------------------------------------- QKV gemm
__global__ __launch_bounds__(256) void qkv_gemm(
    const unsigned short* __restrict__ Xq, const unsigned short* __restrict__ Xk,
    const unsigned short* __restrict__ Xv,
    const unsigned short* __restrict__ Wq, const unsigned short* __restrict__ Wk,
    const unsigned short* __restrict__ Wv,
    const float* __restrict__ bq, const float* __restrict__ bk,
    const float* __restrict__ bv,
    unsigned short* __restrict__ Oq, unsigned short* __restrict__ Ok,
    unsigned short* __restrict__ Ov) {
  __shared__ unsigned short As[128 * 32], Bs[128 * 32];
  const int z = blockIdx.z;
  const unsigned short* A  = (z == 0) ? Xq : (z == 1) ? Xk : Xv;
  const unsigned short* Bt = (z == 0) ? Wq : (z == 1) ? Wk : Wv;
  const float* bias        = (z == 0) ? bq : (z == 1) ? bk : bv;
  unsigned short* O        = (z == 0) ? Oq : (z == 1) ? Ok : Ov;
  const float scale = (z == 0) ? 0.125f : 1.0f;

  const int m0 = blockIdx.x * 128, n0 = blockIdx.y * 128;
  f32x4 acc[4][4] = {};
  gemm_core(A, Bt, As, Bs, m0, n0, threadIdx.x, acc);

  const int tid = threadIdx.x, w = tid >> 6, l = tid & 63;
  const int wm = w >> 1, wn = w & 1, lr = l & 15, lg = l >> 4;
#pragma unroll
  for (int n = 0; n < 4; n++) {
    const int ng = n0 + wn * 64 + n * 16 + lr;
    const float bvv = bias[ng];
    const int h = ng >> 6, d = ng & 63;
#pragma unroll
    for (int m = 0; m < 4; m++) {
#pragma unroll
      for (int r = 0; r < 4; r++) {
        const int mg = m0 + wm * 64 + m * 16 + lg * 4 + r;
        const int b = mg >> 11, s = mg & 2047;
        O[((size_t)(b * NH_ + h) * S_ + s) * DH_ + d] = f2bf((acc[m][n][r] + bvv) * scale);
      }
    }
  }
}

// ---------------------------------------------------------------- out gemm
__global__ __launch_bounds__(256) void out_gemm(
    const unsigned short* __restrict__ A, const unsigned short* __restrict__ Bt,
    const float* __restrict__ bias, float* __restrict__ out) {
  __shared__ unsigned short As[128 * 32], Bs[128 * 32];
  const int m0 = blockIdx.x * 128, n0 = blockIdx.y * 128;
  f32x4 acc[4][4] = {};
  gemm_core(A, Bt, As, Bs, m0, n0, threadIdx.x, acc);

  const int tid = threadIdx.x, w = tid >> 6, l = tid & 63;
  const int wm = w >> 1, wn = w & 1, lr = l & 15, lg = l >> 4;
#pragma unroll
  for (int n = 0; n < 4; n++) {
    const int ng = n0 + wn * 64 + n * 16 + lr;
    const float bvv = bias[ng];
#pragma unroll
    for (int m = 0; m < 4; m++) {
#pragma unroll
      for (int r = 0; r < 4; r++) {
        const int mg = m0 + wm * 64 + m * 16 + lg * 4 + r;
        out[(size_t)mg * 768 + ng] = acc[m][n][r] + bvv;
      }
    }
  }
}

// ---------------------------------------------------------------- V transpose
// Vp[B,H,S,D] -> Vt[B,H,D,S], per (b,h): [2048][64] -> [64][2048]
__global__ __launch_bounds__(256) void transpose_v(
    const unsigned short* __restrict__ Vp, unsigned short* __restrict__ Vt) {
  __shared__ unsigned short T[64 * 72];
  const int bh = blockIdx.y;
  const int s0 = blockIdx.x * 64;
  const int t = threadIdx.x;
  const int rl = t >> 3, u = t & 7;
#pragma unroll
  for (int i = 0; i < 2; i++) {
    const int s = rl + i * 32;
    short8 v = *(const short8*)&Vp[((size_t)bh * S_ + s0 + s) * DH_ + u * 8];
#pragma unroll
    for (int j = 0; j < 8; j++) T[(u * 8 + j) * 72 + s] = (unsigned short)v[j];
  }
  __syncthreads();
#pragma unroll
  for (int i = 0; i < 2; i++) {
    const int d = rl + i * 32;
    short8 o = *(const short8*)&T[d * 72 + u * 8];
    *(short8*)&Vt[((size_t)bh * DH_ + d) * S_ + s0 + u * 8] = o;
  }
}

// ---------------------------------------------------------------- attention
// Swapped-QK^T flash attention, TLP-oriented: 4 waves x 16 q-rows = 64 q/block,
// 1536 blocks (24 waves/CU offered), VGPR capped via launch_bounds(256,4).
// KV tile = 64 keys read directly from global (L2-resident via XCD swizzle).
// Softmax in-register (lane lr = q); defer-max rescale skip (THR=8);
// P -> bf16 via v_cvt_pk_bf16_f32, per-wave LDS re-layout (no barriers).
__global__ __launch_bounds__(256, 4) void attn_kernel(
    const unsigned short* __restrict__ Qp, const unsigned short* __restrict__ Kp,
    const unsigned short* __restrict__ Vt, const float* __restrict__ maskadd,
    unsigned short* __restrict__ Ctx) {
  __shared__ unsigned short Ps[4][16][72];  // [wave][q][key(+pad)]

  // XCD swizzle: hw assigns xcd = blockIdx % 8; give each bh one XCD
  const int id = blockIdx.x;            // 0..1535
  const int xcd = id & 7, slot = id >> 3;
  const int bh = xcd + 8 * (slot >> 5); // 6 bh per xcd
  const int qt = slot & 31;             // 32 q-tiles of 64
  const int b = bh / NH_, h = bh % NH_;
  const int tid = threadIdx.x, w = tid >> 6, l = tid & 63;
  const int lr = l & 15, lg = l >> 4;
  const int qw = qt * 64 + w * 16;

  // Q fragments (B-operand of S^T): lane lr = q, k-dim = d = lg*8 + ks*32
  const unsigned short* Qb = Qp + ((size_t)bh * S_ + qw + lr) * DH_ + lg * 8;
  const short8 aq0 = *(const short8*)(Qb);
  const short8 aq1 = *(const short8*)(Qb + 32);

  const unsigned short* Kb = Kp + ((size_t)bh * S_ + lr) * DH_ + lg * 8;
  const unsigned short* Vb = Vt + ((size_t)bh * DH_ + lr) * (size_t)S_ + lg * 8;
  const float* Mb = maskadd + b * S_ + lg * 4;

  float m_run = -INFINITY, l_run = 0.f;
  f32x4 ctx[4] = {};
  unsigned short* Pw = &Ps[w][0][0];
  unsigned* Prow = (unsigned*)(Pw + lr * 72);        // write base (u32 units)
  const unsigned short* Prd = Pw + lr * 72 + lg * 8; // read base

  for (int kt = 0; kt < S_ / 64; kt++) {
    const int kv0 = kt * 64;

    // mask addend + V frags issued early (latency hides under QK^T+softmax)
    f32x4 mk[4];
#pragma unroll
    for (int t = 0; t < 4; t++) mk[t] = *(const f32x4*)(Mb + kv0 + 16 * t);
    short8 vf[4][2];
#pragma unroll
    for (int dt = 0; dt < 4; dt++)
#pragma unroll
      for (int ks = 0; ks < 2; ks++)
        vf[dt][ks] = *(const short8*)(Vb + (size_t)(16 * dt) * S_ + kv0 + ks * 32);

    // S^T = K.Q : 8 MFMAs, K frags straight from global (L2)
    f32x4 sacc[4] = {};
    __builtin_amdgcn_s_setprio(1);
#pragma unroll
    for (int t = 0; t < 4; t++) {
      const unsigned short* kp = Kb + (size_t)(kv0 + 16 * t) * DH_;
      short8 kf0 = *(const short8*)(kp);
      short8 kf1 = *(const short8*)(kp + 32);
      sacc[t] = __builtin_amdgcn_mfma_f32_16x16x32_bf16(kf0, aq0, sacc[t], 0, 0, 0);
      sacc[t] = __builtin_amdgcn_mfma_f32_16x16x32_bf16(kf1, aq1, sacc[t], 0, 0, 0);
    }
    __builtin_amdgcn_s_setprio(0);

#pragma unroll
    for (int t = 0; t < 4; t++)
#pragma unroll
      for (int r = 0; r < 4; r++) sacc[t][r] += mk[t][r];

    // online softmax for q = lr (16 values/lane), cross-group 2 shfl
    float mx = sacc[0][0];
#pragma unroll
    for (int t = 0; t < 4; t++)
#pragma unroll
      for (int r = 0; r < 4; r++)
        if (t || r) mx = fmaxf(mx, sacc[t][r]);
    mx = fmaxf(mx, __shfl_xor(mx, 16));
    mx = fmaxf(mx, __shfl_xor(mx, 32));

    // defer-max: skip rescale when max growth <= 8 for ALL q (wave-uniform)
    if (!__all(mx <= m_run + 8.f)) {
      const float nm = fmaxf(m_run, mx);
      const float al = __expf(m_run - nm);
      m_run = nm;
      l_run *= al;
      float av[4];
#pragma unroll
      for (int r = 0; r < 4; r++) av[r] = __shfl(al, lg * 4 + r, 16);
#pragma unroll
      for (int dt = 0; dt < 4; dt++)
#pragma unroll
        for (int r = 0; r < 4; r++) ctx[dt][r] *= av[r];
    }

    float ts = 0.f;
#pragma unroll
    for (int t = 0; t < 4; t++)
#pragma unroll
      for (int r = 0; r < 4; r++) {
        const float p = __expf(sacc[t][r] - m_run);
        sacc[t][r] = p; ts += p;
      }
    ts += __shfl_xor(ts, 16);
    ts += __shfl_xor(ts, 32);
    l_run += ts;

    // P -> bf16 via cvt_pk, store u32x2 per key-subtile (per-wave, no barrier)
#pragma unroll
    for (int t = 0; t < 4; t++) {
      u32x2 c;
      c.x = cvtpk_bf16(sacc[t][0], sacc[t][1]);
      c.y = cvtpk_bf16(sacc[t][2], sacc[t][3]);
      *(u32x2*)(Prow + 8 * t + lg * 2) = c;
    }
    const short8 pa0 = *(const short8*)(Prd);
    const short8 pa1 = *(const short8*)(Prd + 32);

    // PV: A = P (lane lr = q), B = Vt fragment
    __builtin_amdgcn_s_setprio(1);
#pragma unroll
    for (int dt = 0; dt < 4; dt++) {
      ctx[dt] = __builtin_amdgcn_mfma_f32_16x16x32_bf16(pa0, vf[dt][0], ctx[dt], 0, 0, 0);
      ctx[dt] = __builtin_amdgcn_mfma_f32_16x16x32_bf16(pa1, vf[dt][1], ctx[dt], 0, 0, 0);
    }
    __builtin_amdgcn_s_setprio(0);
  }

  // epilogue: normalize, write bf16 ctx
  const float linv = 1.f / l_run;
  float iv[4];
#pragma unroll
  for (int r = 0; r < 4; r++) iv[r] = __shfl(linv, lg * 4 + r, 16);
#pragma unroll
  for (int r = 0; r < 4; r++) {
    const int qg = qw + lg * 4 + r;
#pragma unroll
    for (int dt = 0; dt < 4; dt++) {
      Ctx[((size_t)b * S_ + qg) * D_ + h * DH_ + dt * 16 + lr] =
          f2bf(ctx[dt][r] * iv[r]);
    }
  }
}

// ---------------------------------------------------------------- launcher
extern "C" void kernel_launch(void* const* d_in, const int* in_sizes, int n_in,
                              void* d_out, int out_size, void* d_ws, size_t ws_size,
                              hipStream_t stream) {
  const float* q   = (const float*)d_in[0];
  const float* k   = (const float*)d_in[1];
  const float* v   = (const float*)d_in[2];
  const int* mask  = (const int*)d_in[3];
  const float* q_w = (const float*)d_in[4];
  const float* q_b = (const float*)d_in[5];
  const float* k_w = (const float*)d_in[6];
  const float* k_b = (const float*)d_in[7];
  const float* v_w = (const float*)d_in[8];
  const float* v_b = (const float*)d_in[9];
  const float* o_w = (const float*)d_in[10];
  const float* o_b = (const float*)d_in[11];
  float* out = (float*)d_out;

  unsigned short* ws = (unsigned short*)d_ws;
  unsigned short* Xq = ws;
  unsigned short* Xk = Xq + NX;
  unsigned short* Xv = Xk + NX;
  unsigned short* Wq = Xv + NX;   // Wq..Wo contiguous (convert writes combined)
  unsigned short* Wk = Wq + NW;
  unsigned short* Wv = Wk + NW;
  unsigned short* Wo = Wv + NW;
  unsigned short* Qp = Wo + NW;
  unsigned short* Kp = Qp + NX;
  unsigned short* Vp = Kp + NX;
  float* Ma = (float*)(Vp + NX);          // mask addend table, 4x2048 f32
  unsigned short* Vt  = Xk;  // alias: Xk dead after its GEMM
  unsigned short* Ctx = Xq;  // alias: Xq dead after its GEMM

  convert_kernel<<<dim3(20744), dim3(256), 0, stream>>>(
      q, k, v, q_w, k_w, v_w, o_w, mask, Xq, Xk, Xv, Wq, Ma);

  qkv_gemm<<<dim3(64, 6, 3), dim3(256), 0, stream>>>(
      Xq, Xk, Xv, Wq, Wk, Wv, q_b, k_b, v_b, Qp, Kp, Vp);

  transpose_v<<<dim3(32, 48), dim3(256), 0, stream>>>(Vp, Vt);

  attn_kernel<<<dim3(1536), dim3(256), 0, stream>>>(Qp, Kp, Vt, Ma, Ctx);

  out_gemm<<<dim3(64, 6), dim3(256), 0, stream>>>(Ctx, Wo, o_b, out);
}

// Round 4
// 195.379 us; speedup vs baseline: 2.3079x; 2.3079x over previous
//
#include <hip/hip_runtime.h>
#include <hip/hip_bf16.h>

typedef __attribute__((ext_vector_type(8))) short short8;
typedef __attribute__((ext_vector_type(4))) float f32x4;
typedef __attribute__((ext_vector_type(4))) unsigned short u16x4;
typedef __attribute__((ext_vector_type(4))) int int4v;
typedef __attribute__((ext_vector_type(2))) unsigned int u32x2;

#define DEVI static __device__ __forceinline__

constexpr int B_ = 4, S_ = 2048, D_ = 768, NH_ = 12, DH_ = 64;
constexpr int M_ = B_ * S_;                 // 8192
constexpr size_t NX = (size_t)M_ * D_;      // 6291456 elems
constexpr size_t NW = (size_t)D_ * D_;      // 589824 elems

DEVI unsigned short f2bf(float f) {
  union { float f; unsigned u; } c; c.f = f;
  unsigned u = c.u;
  return (unsigned short)((u + 0x7FFFu + ((u >> 16) & 1u)) >> 16);  // RNE
}

DEVI unsigned cvtpk_bf16(float lo, float hi) {
  unsigned r;
  asm("v_cvt_pk_bf16_f32 %0, %1, %2" : "=v"(r) : "v"(lo), "v"(hi));
  return r;  // low16 = bf16(lo), high16 = bf16(hi)
}

DEVI void gload16(const void* g, void* l) {
  __builtin_amdgcn_global_load_lds(
      (const __attribute__((address_space(1))) void*)g,
      (__attribute__((address_space(3))) void*)l, 16, 0, 0);
}

// ---------------------------------------------------------------- convert
// 1D packed grid: [0,18432) X segs, [18432,20736) W combined, [20736,20744) mask
__global__ __launch_bounds__(256) void convert_kernel(
    const float* __restrict__ q, const float* __restrict__ k,
    const float* __restrict__ v, const float* __restrict__ qw_,
    const float* __restrict__ kw_, const float* __restrict__ vw_,
    const float* __restrict__ ow_, const int* __restrict__ smask,
    unsigned short* __restrict__ Xq, unsigned short* __restrict__ Xk,
    unsigned short* __restrict__ Xv, unsigned short* __restrict__ Wc,
    float* __restrict__ dmask) {
  const long bid = blockIdx.x;
  const int tid = threadIdx.x;
  if (bid < 18432) {
    const int seg = (int)(bid / 6144);
    const long i = (bid % 6144) * 256 + tid;
    const float* src = seg == 0 ? q : seg == 1 ? k : v;
    unsigned short* dst = seg == 0 ? Xq : seg == 1 ? Xk : Xv;
    f32x4 vv = *(const f32x4*)(src + i * 4);
    u16x4 o;
    o.x = f2bf(vv.x); o.y = f2bf(vv.y); o.z = f2bf(vv.z); o.w = f2bf(vv.w);
    *(u16x4*)(dst + i * 4) = o;
  } else if (bid < 20736) {
    const long e = ((bid - 18432) * 256 + tid) * 4;  // elem in [0, 4*NW)
    const int j = (int)(e / (long)NW);
    const float* src = j == 0 ? qw_ : j == 1 ? kw_ : j == 2 ? vw_ : ow_;
    f32x4 vv = *(const f32x4*)(src + (e - (long)j * NW));
    u16x4 o;
    o.x = f2bf(vv.x); o.y = f2bf(vv.y); o.z = f2bf(vv.z); o.w = f2bf(vv.w);
    *(u16x4*)(Wc + e) = o;
  } else {
    const long i = (bid - 20736) * 256 + tid;
    int4v m = *(const int4v*)(smask + i * 4);
    f32x4 o;
    o.x = m.x ? 0.f : -1e30f; o.y = m.y ? 0.f : -1e30f;
    o.z = m.z ? 0.f : -1e30f; o.w = m.w ? 0.f : -1e30f;
    *(f32x4*)(dmask + i * 4) = o;
  }
}

// ---------------------------------------------------------------- gemm core
DEVI void gemm_core(const unsigned short* __restrict__ A,
                    const unsigned short* __restrict__ Bt,
                    unsigned short* As, unsigned short* Bs,
                    int m0, int n0, int tid, f32x4 acc[4][4]) {
  const int w = tid >> 6, l = tid & 63;
  const int wm = w >> 1, wn = w & 1;
  const int lr = l & 15, lg = l >> 4;

  const unsigned short* gA0 = A  + (size_t)(m0 + (tid >> 2)) * 768 + (tid & 3) * 8;
  const unsigned short* gB0 = Bt + (size_t)(n0 + (tid >> 2)) * 768 + (tid & 3) * 8;
  unsigned short* lA0 = As + (size_t)(w * 64) * 8;  // wave-uniform LDS base
  unsigned short* lB0 = Bs + (size_t)(w * 64) * 8;
  const unsigned short* fA = As + (size_t)(wm * 64 + lr) * 32 + lg * 8;
  const unsigned short* fB = Bs + (size_t)(wn * 64 + lr) * 32 + lg * 8;

  for (int k0 = 0; k0 < 768; k0 += 32) {
    __syncthreads();
    gload16(gA0 + k0, lA0);
    gload16(gA0 + (size_t)64 * 768 + k0, lA0 + 2048);
    gload16(gB0 + k0, lB0);
    gload16(gB0 + (size_t)64 * 768 + k0, lB0 + 2048);
    __syncthreads();
    short8 af[4], bf[4];
#pragma unroll
    for (int m = 0; m < 4; m++) af[m] = *(const short8*)(fA + m * 16 * 32);
#pragma unroll
    for (int n = 0; n < 4; n++) bf[n] = *(const short8*)(fB + n * 16 * 32);
#pragma unroll
    for (int m = 0; m < 4; m++)
#pragma unroll
      for (int n = 0; n < 4; n++)
        acc[m][n] = __builtin_amdgcn_mfma_f32_16x16x32_bf16(af[m], bf[n], acc[m][n], 0, 0, 0);
  }
}

// ---------------------------------------------------------------- QKV gemm
__global__ __launch_bounds__(256) void qkv_gemm(
    const unsigned short* __restrict__ Xq, const unsigned short* __restrict__ Xk,
    const unsigned short* __restrict__ Xv,
    const unsigned short* __restrict__ Wq, const unsigned short* __restrict__ Wk,
    const unsigned short* __restrict__ Wv,
    const float* __restrict__ bq, const float* __restrict__ bk,
    const float* __restrict__ bv,
    unsigned short* __restrict__ Oq, unsigned short* __restrict__ Ok,
    unsigned short* __restrict__ Ov) {
  __shared__ unsigned short As[128 * 32], Bs[128 * 32];
  const int z = blockIdx.z;
  const unsigned short* A  = (z == 0) ? Xq : (z == 1) ? Xk : Xv;
  const unsigned short* Bt = (z == 0) ? Wq : (z == 1) ? Wk : Wv;
  const float* bias        = (z == 0) ? bq : (z == 1) ? bk : bv;
  unsigned short* O        = (z == 0) ? Oq : (z == 1) ? Ok : Ov;
  const float scale = (z == 0) ? 0.125f : 1.0f;

  const int m0 = blockIdx.x * 128, n0 = blockIdx.y * 128;
  f32x4 acc[4][4] = {};
  gemm_core(A, Bt, As, Bs, m0, n0, threadIdx.x, acc);

  const int tid = threadIdx.x, w = tid >> 6, l = tid & 63;
  const int wm = w >> 1, wn = w & 1, lr = l & 15, lg = l >> 4;
#pragma unroll
  for (int n = 0; n < 4; n++) {
    const int ng = n0 + wn * 64 + n * 16 + lr;
    const float bvv = bias[ng];
    const int h = ng >> 6, d = ng & 63;
#pragma unroll
    for (int m = 0; m < 4; m++) {
#pragma unroll
      for (int r = 0; r < 4; r++) {
        const int mg = m0 + wm * 64 + m * 16 + lg * 4 + r;
        const int b = mg >> 11, s = mg & 2047;
        O[((size_t)(b * NH_ + h) * S_ + s) * DH_ + d] = f2bf((acc[m][n][r] + bvv) * scale);
      }
    }
  }
}

// ---------------------------------------------------------------- out gemm
__global__ __launch_bounds__(256) void out_gemm(
    const unsigned short* __restrict__ A, const unsigned short* __restrict__ Bt,
    const float* __restrict__ bias, float* __restrict__ out) {
  __shared__ unsigned short As[128 * 32], Bs[128 * 32];
  const int m0 = blockIdx.x * 128, n0 = blockIdx.y * 128;
  f32x4 acc[4][4] = {};
  gemm_core(A, Bt, As, Bs, m0, n0, threadIdx.x, acc);

  const int tid = threadIdx.x, w = tid >> 6, l = tid & 63;
  const int wm = w >> 1, wn = w & 1, lr = l & 15, lg = l >> 4;
#pragma unroll
  for (int n = 0; n < 4; n++) {
    const int ng = n0 + wn * 64 + n * 16 + lr;
    const float bvv = bias[ng];
#pragma unroll
    for (int m = 0; m < 4; m++) {
#pragma unroll
      for (int r = 0; r < 4; r++) {
        const int mg = m0 + wm * 64 + m * 16 + lg * 4 + r;
        out[(size_t)mg * 768 + ng] = acc[m][n][r] + bvv;
      }
    }
  }
}

// ---------------------------------------------------------------- V transpose
__global__ __launch_bounds__(256) void transpose_v(
    const unsigned short* __restrict__ Vp, unsigned short* __restrict__ Vt) {
  __shared__ unsigned short T[64 * 72];
  const int bh = blockIdx.y;
  const int s0 = blockIdx.x * 64;
  const int t = threadIdx.x;
  const int rl = t >> 3, u = t & 7;
#pragma unroll
  for (int i = 0; i < 2; i++) {
    const int s = rl + i * 32;
    short8 v = *(const short8*)&Vp[((size_t)bh * S_ + s0 + s) * DH_ + u * 8];
#pragma unroll
    for (int j = 0; j < 8; j++) T[(u * 8 + j) * 72 + s] = (unsigned short)v[j];
  }
  __syncthreads();
#pragma unroll
  for (int i = 0; i < 2; i++) {
    const int d = rl + i * 32;
    short8 o = *(const short8*)&T[d * 72 + u * 8];
    *(short8*)&Vt[((size_t)bh * DH_ + d) * S_ + s0 + u * 8] = o;
  }
}

// ---------------------------------------------------------------- attention
// Swapped-QK^T flash attn, LDS-pipelined (T3 minimum 2-phase):
// 4 waves x 32 q-rows = 128 q/block, grid 768 (XCD-swizzled, 6 bh/XCD).
// KV tile = 64 keys; K[64x64] and V[64x64] double-buffered in LDS via
// global_load_lds with pre-swizzled SOURCE addresses (rule #21): linear LDS
// dest, read side applies c16 ^= (row&7) -> conflict-free ds_read_b128.
// STAGE(kt+1) issued before compute(kt); ONE __syncthreads per tile.
__global__ __launch_bounds__(256) void attn_kernel(
    const unsigned short* __restrict__ Qp, const unsigned short* __restrict__ Kp,
    const unsigned short* __restrict__ Vt, const float* __restrict__ maskadd,
    unsigned short* __restrict__ Ctx) {
  __shared__ unsigned short KsA[4096], KsB[4096];  // [key][d] swizzled, 8KB each
  __shared__ unsigned short VsA[4096], VsB[4096];  // [d][key] swizzled
  __shared__ unsigned short Ps[4][16][72];         // per-wave P relayout buffer

  // XCD swizzle: xcd = id & 7 (hw maps blockIdx%8 -> XCD); 6 bh per XCD
  const int id = blockIdx.x;             // 0..767
  const int xcd = id & 7, slot = id >> 3;  // 96 slots
  const int bh = xcd + 8 * (slot >> 4);  // 48 bh
  const int qt = slot & 15;              // 16 q-tiles of 128
  const int b = bh / NH_, h = bh % NH_;
  const int tid = threadIdx.x, w = tid >> 6, l = tid & 63;
  const int lr = l & 15, lg = l >> 4;
  const int rsw = lr & 7;
  const int qw = qt * 128 + w * 32;

  // Q fragments (B-operand of S^T): lane lr = q, k-dim d = lg*8 + ks*32
  short8 aq[2][2];
#pragma unroll
  for (int qb = 0; qb < 2; qb++)
#pragma unroll
    for (int ks = 0; ks < 2; ks++)
      aq[qb][ks] = *(const short8*)&Qp[((size_t)bh * S_ + qw + qb * 16 + lr) * DH_ +
                                       lg * 8 + ks * 32];

  // staging addresses: thread covers LDS 16B-units {tid, tid+256};
  // unit u: row=u>>3, c=u&7; source column unit cg = c ^ (row&7) (involution)
  const int r0 = tid >> 3, c0 = tid & 7;
  const int cg = c0 ^ (r0 & 7);
  const unsigned short* Kg0 = Kp + ((size_t)bh * S_ + r0) * DH_ + cg * 8;
  const unsigned short* Kg1 = Kg0 + (size_t)32 * DH_;
  const unsigned short* Vg0 = Vt + ((size_t)bh * DH_ + r0) * S_ + cg * 8;
  const unsigned short* Vg1 = Vg0 + (size_t)32 * S_;
  const int wslot = w * 512;  // wave-uniform LDS offset (64 units x 8 halves)

  const float* Mb = maskadd + b * S_ + lg * 4;

  float m_run[2], l_run[2];
  f32x4 ctx[2][4] = {};
#pragma unroll
  for (int qb = 0; qb < 2; qb++) { m_run[qb] = -INFINITY; l_run[qb] = 0.f; }

  unsigned short* Pw = &Ps[w][0][0];
  unsigned* Prow = (unsigned*)(Pw + lr * 72);
  const unsigned short* Prd = Pw + lr * 72 + lg * 8;

  unsigned short *Krd = KsA, *Vrd = VsA, *Kwr = KsB, *Vwr = VsB;

  // prologue: stage tile 0
  {
    gload16(Kg0, KsA + wslot);
    gload16(Kg1, KsA + 2048 + wslot);
    gload16(Vg0, VsA + wslot);
    gload16(Vg1, VsA + 2048 + wslot);
  }
  __syncthreads();

  for (int kt = 0; kt < S_ / 64; kt++) {
    // ---- stage NEXT tile into write buffer (async, drains at end barrier)
    if (kt + 1 < S_ / 64) {
      const size_t ko = (size_t)(kt + 1) * 64 * DH_;
      const int vo = (kt + 1) * 64;
      gload16(Kg0 + ko, Kwr + wslot);
      gload16(Kg1 + ko, Kwr + 2048 + wslot);
      gload16(Vg0 + vo, Vwr + wslot);
      gload16(Vg1 + vo, Vwr + 2048 + wslot);
    }

    // ---- mask addend (L2-hot)
    const int kv0 = kt * 64;
    f32x4 mk[4];
#pragma unroll
    for (int t = 0; t < 4; t++) mk[t] = *(const f32x4*)(Mb + kv0 + 16 * t);

    // ---- S^T = K.Q from LDS (swizzled reads), both q sub-blocks share kf
    f32x4 sacc[2][4] = {};
    __builtin_amdgcn_s_setprio(1);
#pragma unroll
    for (int t = 0; t < 4; t++) {
      const int row = 16 * t + lr;
      short8 kf0 = *(const short8*)&Krd[row * 64 + ((lg) ^ rsw) * 8];
      short8 kf1 = *(const short8*)&Krd[row * 64 + ((lg + 4) ^ rsw) * 8];
      sacc[0][t] = __builtin_amdgcn_mfma_f32_16x16x32_bf16(kf0, aq[0][0], sacc[0][t], 0, 0, 0);
      sacc[0][t] = __builtin_amdgcn_mfma_f32_16x16x32_bf16(kf1, aq[0][1], sacc[0][t], 0, 0, 0);
      sacc[1][t] = __builtin_amdgcn_mfma_f32_16x16x32_bf16(kf0, aq[1][0], sacc[1][t], 0, 0, 0);
      sacc[1][t] = __builtin_amdgcn_mfma_f32_16x16x32_bf16(kf1, aq[1][1], sacc[1][t], 0, 0, 0);
    }
    __builtin_amdgcn_s_setprio(0);

    // ---- softmax per q sub-block; P -> per-wave LDS -> pa regs
    short8 pa[2][2];
#pragma unroll
    for (int qb = 0; qb < 2; qb++) {
#pragma unroll
      for (int t = 0; t < 4; t++)
#pragma unroll
        for (int r = 0; r < 4; r++) sacc[qb][t][r] += mk[t][r];

      float mx = sacc[qb][0][0];
#pragma unroll
      for (int t = 0; t < 4; t++)
#pragma unroll
        for (int r = 0; r < 4; r++)
          if (t || r) mx = fmaxf(mx, sacc[qb][t][r]);
      mx = fmaxf(mx, __shfl_xor(mx, 16));
      mx = fmaxf(mx, __shfl_xor(mx, 32));

      // defer-max: skip rescale when max growth <= 8 for ALL q (wave-uniform)
      if (!__all(mx <= m_run[qb] + 8.f)) {
        const float nm = fmaxf(m_run[qb], mx);
        const float al = __expf(m_run[qb] - nm);
        m_run[qb] = nm;
        l_run[qb] *= al;
        float av[4];
#pragma unroll
        for (int r = 0; r < 4; r++) av[r] = __shfl(al, lg * 4 + r, 16);
#pragma unroll
        for (int dt = 0; dt < 4; dt++)
#pragma unroll
          for (int r = 0; r < 4; r++) ctx[qb][dt][r] *= av[r];
      }

      float ts = 0.f;
#pragma unroll
      for (int t = 0; t < 4; t++)
#pragma unroll
        for (int r = 0; r < 4; r++) {
          const float p = __expf(sacc[qb][t][r] - m_run[qb]);
          sacc[qb][t][r] = p; ts += p;
        }
      ts += __shfl_xor(ts, 16);
      ts += __shfl_xor(ts, 32);
      l_run[qb] += ts;

      // P -> bf16 (cvt_pk) -> per-wave LDS row -> A-fragment regs
#pragma unroll
      for (int t = 0; t < 4; t++) {
        u32x2 c;
        c.x = cvtpk_bf16(sacc[qb][t][0], sacc[qb][t][1]);
        c.y = cvtpk_bf16(sacc[qb][t][2], sacc[qb][t][3]);
        *(u32x2*)(Prow + 8 * t + lg * 2) = c;
      }
      pa[qb][0] = *(const short8*)(Prd);
      pa[qb][1] = *(const short8*)(Prd + 32);
    }

    // ---- PV: vf read once, shared by both q sub-blocks
    __builtin_amdgcn_s_setprio(1);
#pragma unroll
    for (int dt = 0; dt < 4; dt++) {
      const int row = 16 * dt + lr;
      short8 vf0 = *(const short8*)&Vrd[row * 64 + ((lg) ^ rsw) * 8];
      short8 vf1 = *(const short8*)&Vrd[row * 64 + ((lg + 4) ^ rsw) * 8];
      ctx[0][dt] = __builtin_amdgcn_mfma_f32_16x16x32_bf16(pa[0][0], vf0, ctx[0][dt], 0, 0, 0);
      ctx[0][dt] = __builtin_amdgcn_mfma_f32_16x16x32_bf16(pa[0][1], vf1, ctx[0][dt], 0, 0, 0);
      ctx[1][dt] = __builtin_amdgcn_mfma_f32_16x16x32_bf16(pa[1][0], vf0, ctx[1][dt], 0, 0, 0);
      ctx[1][dt] = __builtin_amdgcn_mfma_f32_16x16x32_bf16(pa[1][1], vf1, ctx[1][dt], 0, 0, 0);
    }
    __builtin_amdgcn_s_setprio(0);

    // ---- single barrier per tile: drains stage (vmcnt0) + protects buffers
    __syncthreads();
    unsigned short* t0 = Krd; Krd = Kwr; Kwr = t0;
    unsigned short* t1 = Vrd; Vrd = Vwr; Vwr = t1;
  }

  // ---- epilogue: normalize, write bf16 ctx
#pragma unroll
  for (int qb = 0; qb < 2; qb++) {
    const float linv = 1.f / l_run[qb];
    float iv[4];
#pragma unroll
    for (int r = 0; r < 4; r++) iv[r] = __shfl(linv, lg * 4 + r, 16);
#pragma unroll
    for (int r = 0; r < 4; r++) {
      const int qg = qw + qb * 16 + lg * 4 + r;
#pragma unroll
      for (int dt = 0; dt < 4; dt++) {
        Ctx[((size_t)b * S_ + qg) * D_ + h * DH_ + dt * 16 + lr] =
            f2bf(ctx[qb][dt][r] * iv[r]);
      }
    }
  }
}

// ---------------------------------------------------------------- launcher
extern "C" void kernel_launch(void* const* d_in, const int* in_sizes, int n_in,
                              void* d_out, int out_size, void* d_ws, size_t ws_size,
                              hipStream_t stream) {
  const float* q   = (const float*)d_in[0];
  const float* k   = (const float*)d_in[1];
  const float* v   = (const float*)d_in[2];
  const int* mask  = (const int*)d_in[3];
  const float* q_w = (const float*)d_in[4];
  const float* q_b = (const float*)d_in[5];
  const float* k_w = (const float*)d_in[6];
  const float* k_b = (const float*)d_in[7];
  const float* v_w = (const float*)d_in[8];
  const float* v_b = (const float*)d_in[9];
  const float* o_w = (const float*)d_in[10];
  const float* o_b = (const float*)d_in[11];
  float* out = (float*)d_out;

  unsigned short* ws = (unsigned short*)d_ws;
  unsigned short* Xq = ws;
  unsigned short* Xk = Xq + NX;
  unsigned short* Xv = Xk + NX;
  unsigned short* Wq = Xv + NX;   // Wq..Wo contiguous (convert writes combined)
  unsigned short* Wk = Wq + NW;
  unsigned short* Wv = Wk + NW;
  unsigned short* Wo = Wv + NW;
  unsigned short* Qp = Wo + NW;
  unsigned short* Kp = Qp + NX;
  unsigned short* Vp = Kp + NX;
  float* Ma = (float*)(Vp + NX);          // mask addend table, 4x2048 f32
  unsigned short* Vt  = Xk;  // alias: Xk dead after its GEMM
  unsigned short* Ctx = Xq;  // alias: Xq dead after its GEMM

  convert_kernel<<<dim3(20744), dim3(256), 0, stream>>>(
      q, k, v, q_w, k_w, v_w, o_w, mask, Xq, Xk, Xv, Wq, Ma);

  qkv_gemm<<<dim3(64, 6, 3), dim3(256), 0, stream>>>(
      Xq, Xk, Xv, Wq, Wk, Wv, q_b, k_b, v_b, Qp, Kp, Vp);

  transpose_v<<<dim3(32, 48), dim3(256), 0, stream>>>(Vp, Vt);

  attn_kernel<<<dim3(768), dim3(256), 0, stream>>>(Qp, Kp, Vt, Ma, Ctx);

  out_gemm<<<dim3(64, 6), dim3(256), 0, stream>>>(Ctx, Wo, o_b, out);
}